// Round 1
// baseline (251.216 us; speedup 1.0000x reference)
//
#include <hip/hip_runtime.h>
#include <math.h>

#define NGRID 128
#define NG3 (NGRID * NGRID * NGRID)
#define PW 4
#define CH 32
#define RAD 8

constexpr float L_BOX = 10.0f;
constexpr float H = L_BOX / NGRID;   // 0.078125 — exact in fp32

// Exact periodic 1D kernel: inverse DFT of exp(-0.5*(2*pi*j'/NG)^2).
__global__ void init_ker(float* ker) {
    int r = threadIdx.x;
    if (r > RAD) return;
    double acc = 0.0;
    for (int j = 0; j < NGRID; ++j) {
        int jj = (j < NGRID / 2) ? j : j - NGRID;
        double arg = (2.0 * M_PI * jj) / NGRID;   // sigma = h cancels: sigma*k = 2*pi*j'/NG
        double g = exp(-0.5 * arg * arg);
        acc += g * cos((2.0 * M_PI) * ((double)(j * r) / NGRID));
    }
    ker[r] = (float)(acc / NGRID);
}

__device__ __forceinline__ float silu(float v) {
    return v / (1.0f + expf(-v));
}

// Per-particle window weights + periodic cell indices (matches reference exactly).
__device__ __forceinline__ void window(const float* pos, int i,
                                       float wd[3][PW], int ci[3][PW]) {
#pragma unroll
    for (int d = 0; d < 3; ++d) {
        float pw = fmodf(pos[i * 3 + d], L_BOX);
        int base = (int)floorf(pw / H);          // correctly-rounded fp32 div, like XLA/np
#pragma unroll
        for (int t = 0; t < PW; ++t) {
            int cell = base + t - 1;             // offs = arange(4) - 1
            float dd = (pw - (float)cell * H) / H;
            wd[d][t] = expf(-0.5f * dd * dd);
            ci[d][t] = (cell + NGRID) & (NGRID - 1);
        }
    }
}

__global__ void scatter_kernel(const int* __restrict__ z, const float* __restrict__ pos,
                               const float* __restrict__ emb,
                               const float* __restrict__ W0, const float* __restrict__ b0,
                               const float* __restrict__ W1, const float* __restrict__ b1,
                               float* __restrict__ field, int N) {
    int i = blockIdx.x * blockDim.x + threadIdx.x;
    if (i >= N) return;

    // --- MLP: x = silu(silu(emb[z] @ W0^T + b0) @ W1^T + b1); s = sum_c x ---
    int zi = z[i];
    float x[CH], hbuf[CH];
#pragma unroll
    for (int k = 0; k < CH; ++k) x[k] = emb[zi * CH + k];
#pragma unroll
    for (int j = 0; j < CH; ++j) {
        float acc = b0[j];
#pragma unroll
        for (int k = 0; k < CH; ++k) acc += x[k] * W0[j * CH + k];
        hbuf[j] = silu(acc);
    }
    float s = 0.0f;
#pragma unroll
    for (int j = 0; j < CH; ++j) {
        float acc = b1[j];
#pragma unroll
        for (int k = 0; k < CH; ++k) acc += hbuf[k] * W1[j * CH + k];
        s += silu(acc);
    }

    // --- spread scalar s with Gaussian window ---
    float wd[3][PW];
    int ci[3][PW];
    window(pos, i, wd, ci);

    for (int px = 0; px < PW; ++px) {
        float wx = wd[0][px] * s;
        int ix = ci[0][px];
        for (int py = 0; py < PW; ++py) {
            float wxy = wx * wd[1][py];
            int iyo = ci[1][py] * NGRID + ix;
            for (int pz = 0; pz < PW; ++pz) {
                atomicAdd(&field[ci[2][pz] * (NGRID * NGRID) + iyo], wxy * wd[2][pz]);
            }
        }
    }
}

// In-place circular conv along x (contiguous axis). One block = one row.
__global__ void conv_x(float* __restrict__ field, const float* __restrict__ ker) {
    __shared__ float row[NGRID];
    float k[RAD + 1];
#pragma unroll
    for (int r = 0; r <= RAD; ++r) k[r] = ker[r];
    int base = blockIdx.x * NGRID;
    int t = threadIdx.x;
    row[t] = field[base + t];
    __syncthreads();
    float acc = k[0] * row[t];
#pragma unroll
    for (int r = 1; r <= RAD; ++r)
        acc += k[r] * (row[(t + r) & (NGRID - 1)] + row[(t - r + NGRID) & (NGRID - 1)]);
    field[base + t] = acc;
}

// In-place circular conv along a strided axis. Tile = full conv axis (128) x 64
// contiguous x. blockIdx.y = index along the fixed axis, blockIdx.x = x-tile.
__global__ void conv_strided(float* __restrict__ field, const float* __restrict__ ker,
                             int s_conv, int s_fix) {
    __shared__ float tile[NGRID][64];
    float k[RAD + 1];
#pragma unroll
    for (int r = 0; r <= RAD; ++r) k[r] = ker[r];
    int x0 = blockIdx.x * 64;
    int base = blockIdx.y * s_fix + x0;
    int tid = threadIdx.x;
    int xl = tid & 63;
    int c0 = tid >> 6;  // 0..3
    for (int c = c0; c < NGRID; c += 4)
        tile[c][xl] = field[base + c * s_conv + xl];
    __syncthreads();
    for (int c = c0; c < NGRID; c += 4) {
        float acc = k[0] * tile[c][xl];
#pragma unroll
        for (int r = 1; r <= RAD; ++r)
            acc += k[r] * (tile[(c + r) & (NGRID - 1)][xl] +
                           tile[(c - r + NGRID) & (NGRID - 1)][xl]);
        field[base + c * s_conv + xl] = acc;
    }
}

__global__ void gather_kernel(const float* __restrict__ pos,
                              const float* __restrict__ field,
                              float* __restrict__ out, int N) {
    int i = blockIdx.x * blockDim.x + threadIdx.x;
    if (i >= N) return;
    float wd[3][PW];
    int ci[3][PW];
    window(pos, i, wd, ci);
    float e = 0.0f;
    for (int px = 0; px < PW; ++px) {
        float wx = wd[0][px];
        int ix = ci[0][px];
        for (int py = 0; py < PW; ++py) {
            float wxy = wx * wd[1][py];
            int iyo = ci[1][py] * NGRID + ix;
            for (int pz = 0; pz < PW; ++pz) {
                e += wxy * wd[2][pz] * field[ci[2][pz] * (NGRID * NGRID) + iyo];
            }
        }
    }
    out[i] = e;
}

extern "C" void kernel_launch(void* const* d_in, const int* in_sizes, int n_in,
                              void* d_out, int out_size, void* d_ws, size_t ws_size,
                              hipStream_t stream) {
    const int*   z   = (const int*)d_in[0];
    const float* pos = (const float*)d_in[1];
    // d_in[2] = batch: all zeros with NBATCH=1 -> no effect on flat index.
    const float* emb = (const float*)d_in[3];
    const float* W0  = (const float*)d_in[4];
    const float* b0  = (const float*)d_in[5];
    const float* W1  = (const float*)d_in[6];
    const float* b1  = (const float*)d_in[7];
    int N = in_sizes[0];

    float* field = (float*)d_ws;          // NG^3 floats = 8 MB
    float* ker   = field + NG3;           // RAD+1 floats

    hipMemsetAsync(field, 0, NG3 * sizeof(float), stream);
    init_ker<<<1, 64, 0, stream>>>(ker);
    scatter_kernel<<<(N + 255) / 256, 256, 0, stream>>>(z, pos, emb, W0, b0, W1, b1, field, N);
    conv_x<<<NGRID * NGRID, NGRID, 0, stream>>>(field, ker);
    conv_strided<<<dim3(2, NGRID), 256, 0, stream>>>(field, ker, NGRID, NGRID * NGRID); // y
    conv_strided<<<dim3(2, NGRID), 256, 0, stream>>>(field, ker, NGRID * NGRID, NGRID); // z
    gather_kernel<<<(N + 255) / 256, 256, 0, stream>>>(pos, field, (float*)d_out, N);
}

// Round 2
// 168.789 us; speedup vs baseline: 1.4883x; 1.4883x over previous
//
#include <hip/hip_runtime.h>
#include <math.h>

#define NGRID 128
#define NG2 (NGRID * NGRID)
#define NG3 (NGRID * NGRID * NGRID)
#define PW 4
#define CH 32
#define RAD 8

constexpr float L_BOX = 10.0f;
constexpr float H = L_BOX / NGRID;   // 0.078125 — exact in fp32

// Exact periodic 1D kernel: inverse DFT of exp(-0.5*(2*pi*j'/NG)^2).
__global__ void init_ker(float* ker) {
    int r = threadIdx.x;
    if (r > RAD) return;
    double acc = 0.0;
    for (int j = 0; j < NGRID; ++j) {
        int jj = (j < NGRID / 2) ? j : j - NGRID;
        double arg = (2.0 * M_PI * jj) / NGRID;   // sigma = h cancels
        double g = exp(-0.5 * arg * arg);
        acc += g * cos((2.0 * M_PI) * ((double)(j * r) / NGRID));
    }
    ker[r] = (float)(acc / NGRID);
}

__device__ __forceinline__ float silu(float v) {
    return v / (1.0f + expf(-v));
}

// Per-lane window: lane handles tap (px,py,pz); returns weight and flat index.
__device__ __forceinline__ void lane_tap(const float* __restrict__ pos, int i, int lane,
                                         float& w, int& addr) {
    int px = lane & 3, py = (lane >> 2) & 3, pz = (lane >> 4) & 3;
    float pwx = fmodf(pos[i * 3 + 0], L_BOX);
    float pwy = fmodf(pos[i * 3 + 1], L_BOX);
    float pwz = fmodf(pos[i * 3 + 2], L_BOX);
    int bx = (int)floorf(pwx / H);
    int by = (int)floorf(pwy / H);
    int bz = (int)floorf(pwz / H);
    int cx = bx + px - 1, cy = by + py - 1, cz = bz + pz - 1;
    float dx = (pwx - (float)cx * H) / H;
    float dy = (pwy - (float)cy * H) / H;
    float dz = (pwz - (float)cz * H) / H;
    w = expf(-0.5f * dx * dx) * expf(-0.5f * dy * dy) * expf(-0.5f * dz * dz);
    int ix = (cx + NGRID) & (NGRID - 1);
    int iy = (cy + NGRID) & (NGRID - 1);
    int iz = (cz + NGRID) & (NGRID - 1);
    addr = iz * NG2 + iy * NGRID + ix;
}

// One wave per particle. Lanes 0-31 (and 32-63, duplicated) cooperatively
// compute the 32-channel MLP via shuffles; then each of the 64 lanes does
// exactly one atomicAdd for its tap.
__global__ void scatter_wave(const int* __restrict__ z, const float* __restrict__ pos,
                             const float* __restrict__ emb,
                             const float* __restrict__ W0, const float* __restrict__ b0,
                             const float* __restrict__ W1, const float* __restrict__ b1,
                             float* __restrict__ field, int N) {
    int wave = threadIdx.x >> 6;
    int lane = threadIdx.x & 63;
    int i = blockIdx.x * 4 + wave;
    if (i >= N) return;

    int sub = lane & 31;           // channel this lane owns (both halves identical)
    int zi = z[i];
    float x = emb[zi * CH + sub];

    float acc = b0[sub];
#pragma unroll
    for (int k = 0; k < CH; ++k)
        acc = fmaf(__shfl(x, k, 32), W0[sub * CH + k], acc);
    float h1 = silu(acc);

    acc = b1[sub];
#pragma unroll
    for (int k = 0; k < CH; ++k)
        acc = fmaf(__shfl(h1, k, 32), W1[sub * CH + k], acc);
    float s = silu(acc);

    // sum over 32 channels within each half-wave (both halves get same result)
#pragma unroll
    for (int m = 16; m >= 1; m >>= 1) s += __shfl_xor(s, m, 32);

    float w; int addr;
    lane_tap(pos, i, lane, w, addr);
    atomicAdd(&field[addr], w * s);
}

// In-place circular conv along x. 2 rows per 256-thread block.
__global__ void conv_x(float* __restrict__ field, const float* __restrict__ ker) {
    __shared__ float rows[2][NGRID];
    float k[RAD + 1];
#pragma unroll
    for (int r = 0; r <= RAD; ++r) k[r] = ker[r];
    int sub = threadIdx.x >> 7;            // which of the 2 rows
    int t = threadIdx.x & (NGRID - 1);
    int base = (blockIdx.x * 2 + sub) * NGRID;
    rows[sub][t] = field[base + t];
    __syncthreads();
    float acc = k[0] * rows[sub][t];
#pragma unroll
    for (int r = 1; r <= RAD; ++r)
        acc += k[r] * (rows[sub][(t + r) & (NGRID - 1)] +
                       rows[sub][(t - r + NGRID) & (NGRID - 1)]);
    field[base + t] = acc;
}

// In-place circular conv along a strided axis. Tile = 128 (conv axis) x 32 (x).
// blockIdx.y = fixed-axis index, blockIdx.x = x-tile. 256 threads = 32x * 8c.
__global__ void conv_strided(float* __restrict__ field, const float* __restrict__ ker,
                             int s_conv, int s_fix) {
    __shared__ float tile[NGRID][32];
    float k[RAD + 1];
#pragma unroll
    for (int r = 0; r <= RAD; ++r) k[r] = ker[r];
    int x0 = blockIdx.x * 32;
    int base = blockIdx.y * s_fix + x0;
    int xl = threadIdx.x & 31;
    int c0 = threadIdx.x >> 5;             // 0..7
    for (int c = c0; c < NGRID; c += 8)
        tile[c][xl] = field[base + c * s_conv + xl];
    __syncthreads();
    for (int c = c0; c < NGRID; c += 8) {
        float acc = k[0] * tile[c][xl];
#pragma unroll
        for (int r = 1; r <= RAD; ++r)
            acc += k[r] * (tile[(c + r) & (NGRID - 1)][xl] +
                           tile[(c - r + NGRID) & (NGRID - 1)][xl]);
        field[base + c * s_conv + xl] = acc;
    }
}

// One wave per particle: lane reads its tap, butterfly-reduce, lane 0 stores.
__global__ void gather_wave(const float* __restrict__ pos,
                            const float* __restrict__ field,
                            float* __restrict__ out, int N) {
    int wave = threadIdx.x >> 6;
    int lane = threadIdx.x & 63;
    int i = blockIdx.x * 4 + wave;
    if (i >= N) return;
    float w; int addr;
    lane_tap(pos, i, lane, w, addr);
    float e = w * field[addr];
#pragma unroll
    for (int m = 32; m >= 1; m >>= 1) e += __shfl_xor(e, m, 64);
    if (lane == 0) out[i] = e;
}

extern "C" void kernel_launch(void* const* d_in, const int* in_sizes, int n_in,
                              void* d_out, int out_size, void* d_ws, size_t ws_size,
                              hipStream_t stream) {
    const int*   z   = (const int*)d_in[0];
    const float* pos = (const float*)d_in[1];
    // d_in[2] = batch: all zeros with NBATCH=1 -> no effect on flat index.
    const float* emb = (const float*)d_in[3];
    const float* W0  = (const float*)d_in[4];
    const float* b0  = (const float*)d_in[5];
    const float* W1  = (const float*)d_in[6];
    const float* b1  = (const float*)d_in[7];
    int N = in_sizes[0];

    float* field = (float*)d_ws;          // NG^3 floats = 8 MB
    float* ker   = field + NG3;           // RAD+1 floats

    hipMemsetAsync(field, 0, NG3 * sizeof(float), stream);
    init_ker<<<1, 64, 0, stream>>>(ker);
    scatter_wave<<<(N + 3) / 4, 256, 0, stream>>>(z, pos, emb, W0, b0, W1, b1, field, N);
    conv_x<<<NG2 / 2, 256, 0, stream>>>(field, ker);
    conv_strided<<<dim3(4, NGRID), 256, 0, stream>>>(field, ker, NGRID, NG2);  // y axis
    conv_strided<<<dim3(4, NGRID), 256, 0, stream>>>(field, ker, NG2, NGRID);  // z axis
    gather_wave<<<(N + 3) / 4, 256, 0, stream>>>(pos, field, (float*)d_out, N);
}

// Round 3
// 132.730 us; speedup vs baseline: 1.8927x; 1.2717x over previous
//
#include <hip/hip_runtime.h>
#include <math.h>

#define NGRID 128
#define NG2 (NGRID * NGRID)
#define NG3 (NGRID * NGRID * NGRID)
#define PW 4
#define CH 32
#define RAD 8

constexpr float L_BOX = 10.0f;
constexpr float H = L_BOX / NGRID;   // 0.078125 — exact in fp32

// Exact periodic 1D kernel: inverse DFT of exp(-0.5*(2*pi*j'/NG)^2).
// Parallel: block r (0..RAD), thread j (0..127) computes one term; LDS reduce.
__global__ void init_ker(float* ker) {
    __shared__ double sh[NGRID];
    int r = blockIdx.x;
    int j = threadIdx.x;
    int jj = (j < NGRID / 2) ? j : j - NGRID;
    double arg = (2.0 * M_PI * jj) / NGRID;   // sigma = h cancels
    double term = exp(-0.5 * arg * arg) *
                  cos((2.0 * M_PI) * ((double)(j * r) / NGRID));
    sh[j] = term;
    __syncthreads();
#pragma unroll
    for (int s = NGRID / 2; s >= 1; s >>= 1) {
        if (j < s) sh[j] += sh[j + s];
        __syncthreads();
    }
    if (j == 0) ker[r] = (float)(sh[0] / NGRID);
}

__device__ __forceinline__ float silu(float v) {
    return v / (1.0f + expf(-v));
}

// Per-lane window: lane handles tap (px,py,pz); returns weight and flat index.
__device__ __forceinline__ void lane_tap(const float* __restrict__ pos, int i, int lane,
                                         float& w, int& addr) {
    int px = lane & 3, py = (lane >> 2) & 3, pz = (lane >> 4) & 3;
    float pwx = fmodf(pos[i * 3 + 0], L_BOX);
    float pwy = fmodf(pos[i * 3 + 1], L_BOX);
    float pwz = fmodf(pos[i * 3 + 2], L_BOX);
    int bx = (int)floorf(pwx / H);
    int by = (int)floorf(pwy / H);
    int bz = (int)floorf(pwz / H);
    int cx = bx + px - 1, cy = by + py - 1, cz = bz + pz - 1;
    float dx = (pwx - (float)cx * H) / H;
    float dy = (pwy - (float)cy * H) / H;
    float dz = (pwz - (float)cz * H) / H;
    w = expf(-0.5f * dx * dx) * expf(-0.5f * dy * dy) * expf(-0.5f * dz * dz);
    int ix = (cx + NGRID) & (NGRID - 1);
    int iy = (cy + NGRID) & (NGRID - 1);
    int iz = (cz + NGRID) & (NGRID - 1);
    addr = iz * NG2 + iy * NGRID + ix;
}

// One wave per particle. Lanes 0-31 (and 32-63, duplicated) cooperatively
// compute the 32-channel MLP via shuffles; then each of the 64 lanes does
// exactly one atomicAdd for its tap.
__global__ void scatter_wave(const int* __restrict__ z, const float* __restrict__ pos,
                             const float* __restrict__ emb,
                             const float* __restrict__ W0, const float* __restrict__ b0,
                             const float* __restrict__ W1, const float* __restrict__ b1,
                             float* __restrict__ field, int N) {
    int wave = threadIdx.x >> 6;
    int lane = threadIdx.x & 63;
    int i = blockIdx.x * 4 + wave;
    if (i >= N) return;

    int sub = lane & 31;           // channel this lane owns (both halves identical)
    int zi = z[i];
    float x = emb[zi * CH + sub];

    float acc = b0[sub];
#pragma unroll
    for (int k = 0; k < CH; ++k)
        acc = fmaf(__shfl(x, k, 32), W0[sub * CH + k], acc);
    float h1 = silu(acc);

    acc = b1[sub];
#pragma unroll
    for (int k = 0; k < CH; ++k)
        acc = fmaf(__shfl(h1, k, 32), W1[sub * CH + k], acc);
    float s = silu(acc);

    // sum over 32 channels within each half-wave (both halves get same result)
#pragma unroll
    for (int m = 16; m >= 1; m >>= 1) s += __shfl_xor(s, m, 32);

    float w; int addr;
    lane_tap(pos, i, lane, w, addr);
    atomicAdd(&field[addr], w * s);
}

// In-place circular conv along x. 2 rows per 256-thread block.
__global__ void conv_x(float* __restrict__ field, const float* __restrict__ ker) {
    __shared__ float rows[2][NGRID];
    float k[RAD + 1];
#pragma unroll
    for (int r = 0; r <= RAD; ++r) k[r] = ker[r];
    int sub = threadIdx.x >> 7;            // which of the 2 rows
    int t = threadIdx.x & (NGRID - 1);
    int base = (blockIdx.x * 2 + sub) * NGRID;
    rows[sub][t] = field[base + t];
    __syncthreads();
    float acc = k[0] * rows[sub][t];
#pragma unroll
    for (int r = 1; r <= RAD; ++r)
        acc += k[r] * (rows[sub][(t + r) & (NGRID - 1)] +
                       rows[sub][(t - r + NGRID) & (NGRID - 1)]);
    field[base + t] = acc;
}

// In-place circular conv along a strided axis. Tile = 128 (conv axis) x 32 (x).
// blockIdx.y = fixed-axis index, blockIdx.x = x-tile. 256 threads = 32x * 8c.
__global__ void conv_strided(float* __restrict__ field, const float* __restrict__ ker,
                             int s_conv, int s_fix) {
    __shared__ float tile[NGRID][32];
    float k[RAD + 1];
#pragma unroll
    for (int r = 0; r <= RAD; ++r) k[r] = ker[r];
    int x0 = blockIdx.x * 32;
    int base = blockIdx.y * s_fix + x0;
    int xl = threadIdx.x & 31;
    int c0 = threadIdx.x >> 5;             // 0..7
    for (int c = c0; c < NGRID; c += 8)
        tile[c][xl] = field[base + c * s_conv + xl];
    __syncthreads();
    for (int c = c0; c < NGRID; c += 8) {
        float acc = k[0] * tile[c][xl];
#pragma unroll
        for (int r = 1; r <= RAD; ++r)
            acc += k[r] * (tile[(c + r) & (NGRID - 1)][xl] +
                           tile[(c - r + NGRID) & (NGRID - 1)][xl]);
        field[base + c * s_conv + xl] = acc;
    }
}

// One wave per particle: lane reads its tap, butterfly-reduce, lane 0 stores.
__global__ void gather_wave(const float* __restrict__ pos,
                            const float* __restrict__ field,
                            float* __restrict__ out, int N) {
    int wave = threadIdx.x >> 6;
    int lane = threadIdx.x & 63;
    int i = blockIdx.x * 4 + wave;
    if (i >= N) return;
    float w; int addr;
    lane_tap(pos, i, lane, w, addr);
    float e = w * field[addr];
#pragma unroll
    for (int m = 32; m >= 1; m >>= 1) e += __shfl_xor(e, m, 64);
    if (lane == 0) out[i] = e;
}

extern "C" void kernel_launch(void* const* d_in, const int* in_sizes, int n_in,
                              void* d_out, int out_size, void* d_ws, size_t ws_size,
                              hipStream_t stream) {
    const int*   z   = (const int*)d_in[0];
    const float* pos = (const float*)d_in[1];
    // d_in[2] = batch: all zeros with NBATCH=1 -> no effect on flat index.
    const float* emb = (const float*)d_in[3];
    const float* W0  = (const float*)d_in[4];
    const float* b0  = (const float*)d_in[5];
    const float* W1  = (const float*)d_in[6];
    const float* b1  = (const float*)d_in[7];
    int N = in_sizes[0];

    float* field = (float*)d_ws;          // NG^3 floats = 8 MB
    float* ker   = field + NG3;           // RAD+1 floats

    hipMemsetAsync(field, 0, NG3 * sizeof(float), stream);
    init_ker<<<RAD + 1, NGRID, 0, stream>>>(ker);
    scatter_wave<<<(N + 3) / 4, 256, 0, stream>>>(z, pos, emb, W0, b0, W1, b1, field, N);
    conv_x<<<NG2 / 2, 256, 0, stream>>>(field, ker);
    conv_strided<<<dim3(4, NGRID), 256, 0, stream>>>(field, ker, NGRID, NG2);  // y axis
    conv_strided<<<dim3(4, NGRID), 256, 0, stream>>>(field, ker, NG2, NGRID);  // z axis
    gather_wave<<<(N + 3) / 4, 256, 0, stream>>>(pos, field, (float*)d_out, N);
}